// Round 3
// baseline (352.545 us; speedup 1.0000x reference)
//
#include <hip/hip_runtime.h>

#define B_ 32
#define N_ 4096
#define ENC_ 1024
#define DEC_ 512
#define ATT_ 512
#define NT_ 16   // K steps of BK=64

typedef __attribute__((ext_vector_type(8))) short short8;
typedef __attribute__((ext_vector_type(4))) float f32x4;

// fp32 -> bf16 bits, round-to-nearest-even (finite inputs)
__device__ __forceinline__ short f2bf(float f) {
  union { float f; unsigned u; } x; x.f = f;
  unsigned r = (x.u + 0x7FFFu + ((x.u >> 16) & 1u)) >> 16;
  return (short)r;
}

// LDS-only fence + raw barrier: ds ops drain (lgkmcnt), global prefetch loads
// stay IN FLIGHT across the barrier (no vmcnt(0) drain).
__device__ __forceinline__ void lds_barrier() {
  asm volatile("s_waitcnt lgkmcnt(0)" ::: "memory");
  __builtin_amdgcn_s_barrier();
  asm volatile("" ::: "memory");
}

// ---------------------------------------------------------------------------
// Kernel 1: (a) att2[b,a] = dh[b,:]@W_dec[:,a] + b_dec[a] + b_enc[a]
//           (b) W_enc fp32 -> bf16 in MFMA B-fragment order:
//               Wfrag[((c*32+t)*64+l)*8+j] = W_enc[t*32+(l>>4)*8+j][c*16+(l&15)]
// ---------------------------------------------------------------------------
extern "C" __global__ void __launch_bounds__(256) prep_kernel(
    const float* __restrict__ dh, const float* __restrict__ W_dec,
    const float* __restrict__ b_dec, const float* __restrict__ b_enc,
    const float* __restrict__ W_enc,
    float* __restrict__ att2, short* __restrict__ Wfrag)
{
  if (blockIdx.x < B_) {
    __shared__ float dhs[DEC_];
    int b = blockIdx.x;
    for (int i = threadIdx.x; i < DEC_; i += 256) dhs[i] = dh[b * DEC_ + i];
    __syncthreads();
    for (int a = threadIdx.x; a < ATT_; a += 256) {
      float s = b_dec[a] + b_enc[a];
      for (int k = 0; k < DEC_; ++k) s += dhs[k] * W_dec[k * ATT_ + a];
      att2[b * ATT_ + a] = s;
    }
  } else {
    int idx = (blockIdx.x - B_) * 256 + threadIdx.x;  // 0..65535 chunks of 8
    int l = idx & 63;          // lane
    int t = (idx >> 6) & 31;   // k-fragment (32 each of K=32)
    int c = idx >> 11;         // col-fragment (32 of 16 cols)
    int col = c * 16 + (l & 15);
    int kb = t * 32 + (l >> 4) * 8;
    short8 p;
#pragma unroll
    for (int j = 0; j < 8; ++j) p[j] = f2bf(W_enc[(kb + j) * ATT_ + col]);
    *(short8*)(Wfrag + ((long)idx << 3)) = p;
  }
}

// ---------------------------------------------------------------------------
// Kernel 2: fused  e[b,n] = sum_a relu( (enc@W_enc)[n,a] + att2[b,a] ) * w[a]
// Tile 64 rows x 512 cols, 8 waves each 64x64 (acc 16 frags -> AGPR).
// BK=64 (16 steps). Pipeline per body:
//   issue B(t+1)->regs (L2), issue A(t+2)->regs (HBM), ds_read A-frags(t),
//   setprio(1) 32xMFMA setprio(0), convert+ds_write A(t+1), lgkm-barrier.
// Global loads never drained at barriers (counted-vmcnt discipline by
// compiler dataflow); B age = 1 body (~1.8k cyc >> L2 300), A age = 1 body
// (> HBM 900).
// ---------------------------------------------------------------------------
extern "C" __global__ void __launch_bounds__(512) gemm_e_kernel(
    const float* __restrict__ enc, const short* __restrict__ Wfrag,
    const float* __restrict__ att2, const float* __restrict__ w_full,
    float* __restrict__ e_out)
{
  __shared__ __align__(16) short As[2][64 * 64];   // 8 KB each, swizzled
  __shared__ float e_red[64][8];

  const int tid = threadIdx.x;
  const int lane = tid & 63;
  const int w = tid >> 6;                 // wave 0..7 -> cols w*64..w*64+63
  const int blk = blockIdx.x;             // 2048 = 32 batches x 64 row-tiles
  const int b = blk >> 6;
  const int n0 = (blk & 63) * 64;

  // A staging: thread -> (row = tid>>3, 8-float chunk kc = tid&7)
  const int arow = tid >> 3;
  const int akc = tid & 7;
  const float* aptr = enc + ((long)(b * N_ + n0 + arow)) * ENC_ + akc * 8;
  const int awbyte = (arow * 128 + akc * 16) ^ ((arow & 7) << 4);

  // A fragment read byte offsets: row rr = r*16+(lane&15), k-half kk
  int arbyte[4][2];
#pragma unroll
  for (int r = 0; r < 4; ++r) {
    int rr = r * 16 + (lane & 15);
#pragma unroll
    for (int kk = 0; kk < 2; ++kk)
      arbyte[r][kk] = (rr * 128 + (lane >> 4) * 16 + kk * 64) ^ ((rr & 7) << 4);
  }

  // B fragments: frag(c,t32) at Wfrag[(c*32+t32)*512 + lane*8], c = w*4+cc
  const short* bptr = Wfrag + (long)(w * 4) * 16384 + lane * 8;

  f32x4 acc[4][4] = {};
  short8 bfg[2][2][4];   // [buf][k-half][cc]
  f32x4 pAB[2][2];       // [buf][half] A-tile global prefetch

  // ---- prologue: stage A(0) direct, prefetch B(0), A(1)
  {
    f32x4 a0 = *(const f32x4*)(aptr);
    f32x4 a1 = *(const f32x4*)(aptr + 4);
    short8 q;
#pragma unroll
    for (int j = 0; j < 4; ++j) { q[j] = f2bf(a0[j]); q[j + 4] = f2bf(a1[j]); }
    *(short8*)((char*)(&As[0][0]) + awbyte) = q;
  }
#pragma unroll
  for (int cc = 0; cc < 4; ++cc) {
    bfg[0][0][cc] = *(const short8*)(bptr + cc * 16384 + 0 * 512);
    bfg[0][1][cc] = *(const short8*)(bptr + cc * 16384 + 1 * 512);
  }
  pAB[0][0] = *(const f32x4*)(aptr + 64);
  pAB[0][1] = *(const f32x4*)(aptr + 64 + 4);
  lds_barrier();

#define GSTEP(CUR, NXT, T)                                                    \
  {                                                                           \
    if ((T) + 1 < NT_) {                                                      \
      _Pragma("unroll")                                                       \
      for (int cc = 0; cc < 4; ++cc) {                                        \
        bfg[NXT][0][cc] =                                                     \
            *(const short8*)(bptr + cc * 16384 + (2 * ((T) + 1)) * 512);      \
        bfg[NXT][1][cc] =                                                     \
            *(const short8*)(bptr + cc * 16384 + (2 * ((T) + 1) + 1) * 512);  \
      }                                                                       \
    }                                                                         \
    if ((T) + 2 < NT_) {                                                      \
      pAB[NXT][0] = *(const f32x4*)(aptr + ((T) + 2) * 64);                   \
      pAB[NXT][1] = *(const f32x4*)(aptr + ((T) + 2) * 64 + 4);               \
    }                                                                         \
    short8 af[2][4];                                                          \
    _Pragma("unroll")                                                         \
    for (int r = 0; r < 4; ++r) {                                             \
      af[0][r] = *(const short8*)((const char*)(&As[CUR][0]) + arbyte[r][0]); \
      af[1][r] = *(const short8*)((const char*)(&As[CUR][0]) + arbyte[r][1]); \
    }                                                                         \
    __builtin_amdgcn_s_setprio(1);                                            \
    _Pragma("unroll")                                                         \
    for (int cc = 0; cc < 4; ++cc) {                                          \
      _Pragma("unroll")                                                       \
      for (int r = 0; r < 4; ++r) {                                           \
        acc[r][cc] = __builtin_amdgcn_mfma_f32_16x16x32_bf16(                 \
            af[0][r], bfg[CUR][0][cc], acc[r][cc], 0, 0, 0);                  \
        acc[r][cc] = __builtin_amdgcn_mfma_f32_16x16x32_bf16(                 \
            af[1][r], bfg[CUR][1][cc], acc[r][cc], 0, 0, 0);                  \
      }                                                                       \
    }                                                                         \
    __builtin_amdgcn_s_setprio(0);                                            \
    if ((T) + 1 < NT_) {                                                      \
      short8 q;                                                               \
      _Pragma("unroll")                                                       \
      for (int j = 0; j < 4; ++j) {                                           \
        q[j] = f2bf(pAB[CUR][0][j]);                                          \
        q[j + 4] = f2bf(pAB[CUR][1][j]);                                      \
      }                                                                       \
      *(short8*)((char*)(&As[NXT][0]) + awbyte) = q;                          \
    }                                                                         \
    lds_barrier();                                                            \
  }

  for (int tt = 0; tt < NT_; tt += 2) {
    GSTEP(0, 1, tt);
    GSTEP(1, 0, tt + 1);
  }
#undef GSTEP

  // ---- epilogue: e = sum_cols relu(att1 + att2) * w
  const int lq = lane >> 4, lr = lane & 15;
  float at2v[4], wv[4];
#pragma unroll
  for (int c = 0; c < 4; ++c) {
    int col = w * 64 + c * 16 + lr;
    at2v[c] = att2[b * ATT_ + col];
    wv[c] = w_full[col];
  }
#pragma unroll
  for (int r = 0; r < 4; ++r) {
#pragma unroll
    for (int j = 0; j < 4; ++j) {
      float s = 0.f;
#pragma unroll
      for (int c = 0; c < 4; ++c)
        s += fmaxf(acc[r][c][j] + at2v[c], 0.f) * wv[c];
      s += __shfl_xor(s, 1); s += __shfl_xor(s, 2);
      s += __shfl_xor(s, 4); s += __shfl_xor(s, 8);
      if (lr == 0) e_red[r * 16 + lq * 4 + j][w] = s;
    }
  }
  __syncthreads();
  if (tid < 64) {
    float ev = 0.f;
#pragma unroll
    for (int ww = 0; ww < 8; ++ww) ev += e_red[tid][ww];
    e_out[b * N_ + n0 + tid] = ev;
  }
}

// ---------------------------------------------------------------------------
// Kernel 3: softmax over N per batch. 32 blocks x 256 threads x 16 elems.
// ---------------------------------------------------------------------------
extern "C" __global__ void __launch_bounds__(256) softmax_kernel(
    const float* __restrict__ e, float* __restrict__ alpha)
{
  int b = blockIdx.x, tid = threadIdx.x;
  float v[16];
  float m = -1e30f;
#pragma unroll
  for (int i = 0; i < 16; ++i) {
    v[i] = e[b * N_ + i * 256 + tid];
    m = fmaxf(m, v[i]);
  }
  for (int off = 1; off < 64; off <<= 1) m = fmaxf(m, __shfl_xor(m, off));
  __shared__ float redm[4];
  if ((tid & 63) == 0) redm[tid >> 6] = m;
  __syncthreads();
  m = fmaxf(fmaxf(redm[0], redm[1]), fmaxf(redm[2], redm[3]));
  float s = 0.f;
#pragma unroll
  for (int i = 0; i < 16; ++i) { v[i] = expf(v[i] - m); s += v[i]; }
  for (int off = 1; off < 64; off <<= 1) s += __shfl_xor(s, off);
  __shared__ float reds[4];
  if ((tid & 63) == 0) reds[tid >> 6] = s;
  __syncthreads();
  s = reds[0] + reds[1] + reds[2] + reds[3];
  float inv = 1.0f / s;
#pragma unroll
  for (int i = 0; i < 16; ++i) alpha[b * N_ + i * 256 + tid] = v[i] * inv;
}

// ---------------------------------------------------------------------------
// Kernel 4: partial awe. grid = b(32) x cchunk(4, 256 cols) x nchunk(16, 256 n)
// ---------------------------------------------------------------------------
extern "C" __global__ void __launch_bounds__(256) awe_part_kernel(
    const float* __restrict__ enc, const float* __restrict__ alpha,
    float* __restrict__ part)
{
  __shared__ float als[256];
  __shared__ f32x4 red[256];
  int bi = blockIdx.x;
  int b = bi & 31, cchunk = (bi >> 5) & 3, nchunk = bi >> 7;
  int t = threadIdx.x;
  int n0 = nchunk * 256;
  als[t] = alpha[b * N_ + n0 + t];
  __syncthreads();
  int tcol = t & 63, tn = t >> 6;
  const float* base = enc + (long)b * N_ * ENC_ + (long)n0 * ENC_ +
                      cchunk * 256 + tcol * 4;
  f32x4 acc = {};
  for (int i = tn; i < 256; i += 4) {
    f32x4 vv = *(const f32x4*)(base + (long)i * ENC_);
    acc += als[i] * vv;
  }
  red[t] = acc;
  __syncthreads();
  if (t < 64) {
    f32x4 s = red[t] + red[t + 64] + red[t + 128] + red[t + 192];
    *(f32x4*)(&part[(long)nchunk * 32768 + b * 1024 + cchunk * 256 + t * 4]) = s;
  }
}

// Kernel 5: combine the 16 n-partials
extern "C" __global__ void __launch_bounds__(256) awe_reduce_kernel(
    const float* __restrict__ part, float* __restrict__ awe)
{
  int i = blockIdx.x * 256 + threadIdx.x;   // 32768 = 32*1024
  float s = 0.f;
#pragma unroll
  for (int p = 0; p < 16; ++p) s += part[(long)p * 32768 + i];
  awe[i] = s;
}

// ---------------------------------------------------------------------------
extern "C" void kernel_launch(void* const* d_in, const int* in_sizes, int n_in,
                              void* d_out, int out_size, void* d_ws, size_t ws_size,
                              hipStream_t stream) {
  const float* enc    = (const float*)d_in[0];
  const float* dh     = (const float*)d_in[1];
  const float* W_enc  = (const float*)d_in[2];
  const float* b_enc  = (const float*)d_in[3];
  const float* W_dec  = (const float*)d_in[4];
  const float* b_dec  = (const float*)d_in[5];
  const float* w_full = (const float*)d_in[6];
  // d_in[7] = b_full: softmax shift-invariant, unused.
  float* out = (float*)d_out;   // [awe 32*1024 | alpha 32*4096]

  char* ws = (char*)d_ws;
  float* att2  = (float*)ws;                                  // 64 KB
  short* Wfrag = (short*)(ws + 65536);                        // 1 MB
  float* e_buf = (float*)(ws + 65536 + 1048576);              // 512 KB
  float* part  = (float*)(ws + 65536 + 1048576 + 524288);     // 2 MB

  hipLaunchKernelGGL(prep_kernel, dim3(B_ + 256), dim3(256), 0, stream,
                     dh, W_dec, b_dec, b_enc, W_enc, att2, Wfrag);
  hipLaunchKernelGGL(gemm_e_kernel, dim3(2048), dim3(512), 0, stream,
                     enc, Wfrag, att2, w_full, e_buf);
  hipLaunchKernelGGL(softmax_kernel, dim3(B_), dim3(256), 0, stream,
                     e_buf, out + B_ * ENC_);
  hipLaunchKernelGGL(awe_part_kernel, dim3(2048), dim3(256), 0, stream,
                     enc, out + B_ * ENC_, part);
  hipLaunchKernelGGL(awe_reduce_kernel, dim3(128), dim3(256), 0, stream,
                     part, out);
}

// Round 4
// 320.930 us; speedup vs baseline: 1.0985x; 1.0985x over previous
//
#include <hip/hip_runtime.h>

#define B_ 32
#define N_ 4096
#define ENC_ 1024
#define DEC_ 512
#define ATT_ 512

typedef __attribute__((ext_vector_type(8))) short short8;
typedef __attribute__((ext_vector_type(4))) short short4v;
typedef __attribute__((ext_vector_type(4))) float f32x4;

// fp32 -> bf16 bits, round-to-nearest-even (finite inputs)
__device__ __forceinline__ short f2bf(float f) {
  union { float f; unsigned u; } x; x.f = f;
  unsigned r = (x.u + 0x7FFFu + ((x.u >> 16) & 1u)) >> 16;
  return (short)r;
}

// LDS-only fence + raw barrier: ds ops drain (lgkmcnt), global prefetch loads
// stay IN FLIGHT across the barrier (no vmcnt(0) drain).
__device__ __forceinline__ void lds_barrier() {
  asm volatile("s_waitcnt lgkmcnt(0)" ::: "memory");
  __builtin_amdgcn_s_barrier();
  asm volatile("" ::: "memory");
}

// ---------------------------------------------------------------------------
// Kernel 1: (a) att2[b,a] = dh[b,:]@W_dec[:,a] + b_dec[a] + b_enc[a]
//           (b) W_enc fp32 -> bf16 in MFMA B-fragment order:
//               Wfrag[((c*32+t)*64+l)*8+j] = W_enc[t*32+(l>>4)*8+j][c*16+(l&15)]
// ---------------------------------------------------------------------------
extern "C" __global__ void __launch_bounds__(256) prep_kernel(
    const float* __restrict__ dh, const float* __restrict__ W_dec,
    const float* __restrict__ b_dec, const float* __restrict__ b_enc,
    const float* __restrict__ W_enc,
    float* __restrict__ att2, short* __restrict__ Wfrag)
{
  if (blockIdx.x < B_) {
    __shared__ float dhs[DEC_];
    int b = blockIdx.x;
    for (int i = threadIdx.x; i < DEC_; i += 256) dhs[i] = dh[b * DEC_ + i];
    __syncthreads();
    for (int a = threadIdx.x; a < ATT_; a += 256) {
      float s = b_dec[a] + b_enc[a];
      for (int k = 0; k < DEC_; ++k) s += dhs[k] * W_dec[k * ATT_ + a];
      att2[b * ATT_ + a] = s;
    }
  } else {
    int idx = (blockIdx.x - B_) * 256 + threadIdx.x;  // 0..65535 chunks of 8
    int l = idx & 63;          // lane
    int t = (idx >> 6) & 31;   // k-fragment (32 each of K=32)
    int c = idx >> 11;         // col-fragment (32 of 16 cols)
    int col = c * 16 + (l & 15);
    int kb = t * 32 + (l >> 4) * 8;
    short8 p;
#pragma unroll
    for (int j = 0; j < 8; ++j) p[j] = f2bf(W_enc[(kb + j) * ATT_ + col]);
    *(short8*)(Wfrag + ((long)idx << 3)) = p;
  }
}

// ---------------------------------------------------------------------------
// Kernel 2: fused  e[b,n] = sum_a relu( (enc@W_enc)[n,a] + att2[b,a] ) * w[a]
// Tile 64 rows x 512 cols, 8 waves each 64x64.  DESIGNED FOR 2 BLOCKS/CU:
// reg budget ~120 <= 128 (acc 64 AGPR + bfg 16 + af 16 + pA 8 + addr),
// LDS 10 KB.  Two co-resident blocks' barriers interleave -> latency hiding
// without intra-block pipelining.  BK=32, 32 steps:
//   ds_read af(t) -> setprio(1) 16xMFMA setprio(0) -> ds_write A(t+1)
//   -> issue B(t+1) regs (L2) -> issue A(t+3) regs (HBM) -> lgkm-barrier.
// ---------------------------------------------------------------------------
extern "C" __global__ void __launch_bounds__(512, 4) gemm_e_kernel(
    const float* __restrict__ enc, const short* __restrict__ Wfrag,
    const float* __restrict__ att2, const float* __restrict__ w_full,
    float* __restrict__ e_out)
{
  __shared__ __align__(16) short As[2][64 * 32];   // 4 KB each, swizzled
  __shared__ float e_red[64][8];

  const int tid = threadIdx.x;
  const int lane = tid & 63;
  const int w = tid >> 6;                 // wave 0..7 -> cols w*64..w*64+63
  const int blk = blockIdx.x;             // 2048 = 32 batches x 64 row-tiles
  const int b = blk >> 6;
  const int n0 = (blk & 63) * 64;

  // A staging: thread -> (row = tid>>3, 4-float chunk kc = tid&7)
  const int arow = tid >> 3;
  const int akc = tid & 7;
  const float* aptr = enc + ((long)(b * N_ + n0 + arow)) * ENC_ + akc * 4;
  const int awbyte = (arow * 64 + akc * 8) ^ ((arow & 7) << 4);

  // A fragment read byte offsets (swizzled): row rr = r*16 + (lane&15)
  int arbyte[4];
#pragma unroll
  for (int r = 0; r < 4; ++r) {
    int rr = r * 16 + (lane & 15);
    arbyte[r] = (rr * 64 + ((lane >> 4) * 16)) ^ ((rr & 7) << 4);
  }

  // B fragments: frag(c,t) at Wfrag[(c*32+t)*512 + lane*8], c = w*4+cc
  const short* bptr = Wfrag + (long)(w * 4) * 16384 + lane * 8;

  f32x4 acc[4][4] = {};
  short8 bfg[4];
  f32x4 pA0, pA1;

  // ---- prologue: stage A(0) direct, prefetch A(1),A(2), load B(0)
  {
    f32x4 a0 = *(const f32x4*)(aptr);
    short4v q;
#pragma unroll
    for (int j = 0; j < 4; ++j) q[j] = f2bf(a0[j]);
    *(short4v*)((char*)(&As[0][0]) + awbyte) = q;
  }
  pA0 = *(const f32x4*)(aptr + 32);
  pA1 = *(const f32x4*)(aptr + 64);
#pragma unroll
  for (int cc = 0; cc < 4; ++cc)
    bfg[cc] = *(const short8*)(bptr + cc * 16384);
  lds_barrier();

#define GBODY(CUR, NXT, T)                                                  \
  {                                                                         \
    short8 af[4];                                                           \
    _Pragma("unroll")                                                       \
    for (int r = 0; r < 4; ++r)                                             \
      af[r] = *(const short8*)((const char*)(&As[CUR][0]) + arbyte[r]);     \
    __builtin_amdgcn_s_setprio(1);                                          \
    _Pragma("unroll")                                                       \
    for (int cc = 0; cc < 4; ++cc) {                                        \
      _Pragma("unroll")                                                     \
      for (int r = 0; r < 4; ++r)                                           \
        acc[r][cc] = __builtin_amdgcn_mfma_f32_16x16x32_bf16(               \
            af[r], bfg[cc], acc[r][cc], 0, 0, 0);                           \
    }                                                                       \
    __builtin_amdgcn_s_setprio(0);                                          \
    if ((T) < 31) {                                                         \
      short4v qq;                                                           \
      _Pragma("unroll")                                                     \
      for (int j = 0; j < 4; ++j) qq[j] = f2bf(pA0[j]);                     \
      *(short4v*)((char*)(&As[NXT][0]) + awbyte) = qq;                      \
      pA0 = pA1;                                                            \
      _Pragma("unroll")                                                     \
      for (int cc = 0; cc < 4; ++cc)                                        \
        bfg[cc] = *(const short8*)(bptr + cc * 16384 + ((T) + 1) * 512);    \
    }                                                                       \
    if ((T) < 29) pA1 = *(const f32x4*)(aptr + ((T) + 3) * 32);             \
    if ((T) < 31) lds_barrier();                                            \
  }

  for (int tt = 0; tt < 32; tt += 2) {
    GBODY(0, 1, tt);
    GBODY(1, 0, tt + 1);
  }
#undef GBODY

  // ---- epilogue: e = sum_cols relu(att1 + att2) * w
  const int lq = lane >> 4, lr = lane & 15;
  float at2v[4], wv[4];
#pragma unroll
  for (int c = 0; c < 4; ++c) {
    int col = w * 64 + c * 16 + lr;
    at2v[c] = att2[b * ATT_ + col];
    wv[c] = w_full[col];
  }
#pragma unroll
  for (int r = 0; r < 4; ++r) {
#pragma unroll
    for (int j = 0; j < 4; ++j) {
      float s = 0.f;
#pragma unroll
      for (int c = 0; c < 4; ++c)
        s += fmaxf(acc[r][c][j] + at2v[c], 0.f) * wv[c];
      s += __shfl_xor(s, 1); s += __shfl_xor(s, 2);
      s += __shfl_xor(s, 4); s += __shfl_xor(s, 8);
      if (lr == 0) e_red[r * 16 + lq * 4 + j][w] = s;
    }
  }
  __syncthreads();
  if (tid < 64) {
    float ev = 0.f;
#pragma unroll
    for (int ww = 0; ww < 8; ++ww) ev += e_red[tid][ww];
    e_out[b * N_ + n0 + tid] = ev;
  }
}

// ---------------------------------------------------------------------------
// Kernel 3: softmax over N per batch. 32 blocks x 256 threads x 16 elems.
// ---------------------------------------------------------------------------
extern "C" __global__ void __launch_bounds__(256) softmax_kernel(
    const float* __restrict__ e, float* __restrict__ alpha)
{
  int b = blockIdx.x, tid = threadIdx.x;
  float v[16];
  float m = -1e30f;
#pragma unroll
  for (int i = 0; i < 16; ++i) {
    v[i] = e[b * N_ + i * 256 + tid];
    m = fmaxf(m, v[i]);
  }
  for (int off = 1; off < 64; off <<= 1) m = fmaxf(m, __shfl_xor(m, off));
  __shared__ float redm[4];
  if ((tid & 63) == 0) redm[tid >> 6] = m;
  __syncthreads();
  m = fmaxf(fmaxf(redm[0], redm[1]), fmaxf(redm[2], redm[3]));
  float s = 0.f;
#pragma unroll
  for (int i = 0; i < 16; ++i) { v[i] = expf(v[i] - m); s += v[i]; }
  for (int off = 1; off < 64; off <<= 1) s += __shfl_xor(s, off);
  __shared__ float reds[4];
  if ((tid & 63) == 0) reds[tid >> 6] = s;
  __syncthreads();
  s = reds[0] + reds[1] + reds[2] + reds[3];
  float inv = 1.0f / s;
#pragma unroll
  for (int i = 0; i < 16; ++i) alpha[b * N_ + i * 256 + tid] = v[i] * inv;
}

// ---------------------------------------------------------------------------
// Kernel 4: partial awe. grid = b(32) x cchunk(4, 256 cols) x nchunk(16, 256 n)
// ---------------------------------------------------------------------------
extern "C" __global__ void __launch_bounds__(256) awe_part_kernel(
    const float* __restrict__ enc, const float* __restrict__ alpha,
    float* __restrict__ part)
{
  __shared__ float als[256];
  __shared__ f32x4 red[256];
  int bi = blockIdx.x;
  int b = bi & 31, cchunk = (bi >> 5) & 3, nchunk = bi >> 7;
  int t = threadIdx.x;
  int n0 = nchunk * 256;
  als[t] = alpha[b * N_ + n0 + t];
  __syncthreads();
  int tcol = t & 63, tn = t >> 6;
  const float* base = enc + (long)b * N_ * ENC_ + (long)n0 * ENC_ +
                      cchunk * 256 + tcol * 4;
  f32x4 acc = {};
  for (int i = tn; i < 256; i += 4) {
    f32x4 vv = *(const f32x4*)(base + (long)i * ENC_);
    acc += als[i] * vv;
  }
  red[t] = acc;
  __syncthreads();
  if (t < 64) {
    f32x4 s = red[t] + red[t + 64] + red[t + 128] + red[t + 192];
    *(f32x4*)(&part[(long)nchunk * 32768 + b * 1024 + cchunk * 256 + t * 4]) = s;
  }
}

// Kernel 5: combine the 16 n-partials
extern "C" __global__ void __launch_bounds__(256) awe_reduce_kernel(
    const float* __restrict__ part, float* __restrict__ awe)
{
  int i = blockIdx.x * 256 + threadIdx.x;   // 32768 = 32*1024
  float s = 0.f;
#pragma unroll
  for (int p = 0; p < 16; ++p) s += part[(long)p * 32768 + i];
  awe[i] = s;
}

// ---------------------------------------------------------------------------
extern "C" void kernel_launch(void* const* d_in, const int* in_sizes, int n_in,
                              void* d_out, int out_size, void* d_ws, size_t ws_size,
                              hipStream_t stream) {
  const float* enc    = (const float*)d_in[0];
  const float* dh     = (const float*)d_in[1];
  const float* W_enc  = (const float*)d_in[2];
  const float* b_enc  = (const float*)d_in[3];
  const float* W_dec  = (const float*)d_in[4];
  const float* b_dec  = (const float*)d_in[5];
  const float* w_full = (const float*)d_in[6];
  // d_in[7] = b_full: softmax shift-invariant, unused.
  float* out = (float*)d_out;   // [awe 32*1024 | alpha 32*4096]

  char* ws = (char*)d_ws;
  float* att2  = (float*)ws;                                  // 64 KB
  short* Wfrag = (short*)(ws + 65536);                        // 1 MB
  float* e_buf = (float*)(ws + 65536 + 1048576);              // 512 KB
  float* part  = (float*)(ws + 65536 + 1048576 + 524288);     // 2 MB

  hipLaunchKernelGGL(prep_kernel, dim3(B_ + 256), dim3(256), 0, stream,
                     dh, W_dec, b_dec, b_enc, W_enc, att2, Wfrag);
  hipLaunchKernelGGL(gemm_e_kernel, dim3(2048), dim3(512), 0, stream,
                     enc, Wfrag, att2, w_full, e_buf);
  hipLaunchKernelGGL(softmax_kernel, dim3(B_), dim3(256), 0, stream,
                     e_buf, out + B_ * ENC_);
  hipLaunchKernelGGL(awe_part_kernel, dim3(2048), dim3(256), 0, stream,
                     enc, out + B_ * ENC_, part);
  hipLaunchKernelGGL(awe_reduce_kernel, dim3(128), dim3(256), 0, stream,
                     part, out);
}